// Round 3
// baseline (511.933 us; speedup 1.0000x reference)
//
#include <hip/hip_runtime.h>
#include <hip/hip_bf16.h>
#include <math.h>

#define HD   512
#define D2   1024
#define SEQ  4096
#define BAT  16
#define BM   128     // s-rows per block
#define BK   32

typedef _Float16 half8  __attribute__((ext_vector_type(8)));
typedef float    f32x4  __attribute__((ext_vector_type(4)));
typedef float    f32x16 __attribute__((ext_vector_type(16)));

// ---------- kernel 0: W bottom-half -> f16, MFMA-B-frag-major ----------
// Chunk layout (half8 units): (((nh*32 + kt)*2 + q)*2 + kh2)*256 + n
//   value[j] = Wbot[k = kt*32 + q*16 + kh2*8 + j][n_glob = nh*256 + n]
// so scores' B-frag load (lane l: kh2 = l>>5, n = wx*128 + nf*32 + (l&31))
// is one perfectly-coalesced global dwordx4 per (q, nf).
__global__ void wconv_kernel(const float* __restrict__ W, _Float16* __restrict__ WtS) {
  const int kt = blockIdx.x;       // 0..31
  const int nh = blockIdx.y;       // 0..1
  const int t  = threadIdx.x;      // 256
  #pragma unroll
  for (int i = 0; i < 4; ++i) {
    const int c   = i * 256 + t;
    const int q   = c >> 9;
    const int kh2 = (c >> 8) & 1;
    const int n   = c & 255;
    half8 h;
    #pragma unroll
    for (int j = 0; j < 8; ++j)
      h[j] = (_Float16)W[(size_t)(D2 + kt * 32 + q * 16 + kh2 * 8 + j) * HD + nh * 256 + n];
    *(half8*)(WtS + ((size_t)(((nh * 32 + kt) * 2 + q) * 2 + kh2) * 256 + n) * 8) = h;
  }
}

// ---------- kernel 1: h_proj[b,h] = hidden[b,:] . W_top[:,h] (atomic) ----------
__global__ void hproj_kernel(const float* __restrict__ hidden,
                             const float* __restrict__ W,
                             float* __restrict__ hproj) {
  const int b  = blockIdx.x >> 3;
  const int kc = blockIdx.x & 7;
  const int h  = threadIdx.x;
  float a0 = 0.f, a1 = 0.f;
  #pragma unroll 4
  for (int i = 0; i < 128; ++i) {
    const int d = kc * 128 + i;
    const float hd = hidden[b * D2 + d];
    a0 += hd * W[(size_t)d * HD + h];
    a1 += hd * W[(size_t)d * HD + h + 256];
  }
  atomicAdd(&hproj[b * HD + h], a0);
  atomicAdd(&hproj[b * HD + h + 256], a1);
}

// ---------- kernel 2: scores = w_v . tanh(enc.Wbot + h_proj + b_attn) ----------
// 4 waves; wave tile 64x128 (Fm=2, Fn=4 of mfma_f32_32x32x16_f16), block 128x256.
// A: f16 LDS double-buffer, raw s_barrier (lgkmcnt-only drain) so the A global
//    prefetch stays in flight across iterations -> HBM queue saturation.
// B: direct global->VGPR from WtS (L1/L2-resident), no LDS, no barrier coupling.
__global__ __launch_bounds__(256, 2) void scores_kernel(
    const float* __restrict__ enc, const _Float16* __restrict__ WtS,
    const float* __restrict__ hproj, const float* __restrict__ b_attn,
    const float* __restrict__ w_v, float* __restrict__ scores)
{
  __shared__ __align__(16) _Float16 As[2 * 4 * 128 * 8];   // [buf][khalf][row][8]

  const int s0   = blockIdx.x * BM;
  const int nh   = blockIdx.y;
  const int b    = blockIdx.z;
  const int tid  = threadIdx.x, lane = tid & 63, w = tid >> 6;
  const int wy   = w >> 1, wx = w & 1;
  const int llo  = lane & 31, lhi = lane >> 5;

  const float* encB = enc + ((size_t)b * SEQ + s0) * D2;

  // A staging: thread t loads 16 f32 of row (t>>1), k-chunk (t&1)*16
  const int arow = tid >> 1, akc = tid & 1;
  const float* aSrc = encB + (size_t)arow * D2 + akc * 16;

  // B addressing
  const _Float16* Bbase = WtS + (size_t)nh * 32 * 8192
                        + lhi * 2048 + wx * 1024 + llo * 8;

  // A-frag read offsets (16B units scaled to halves)
  int afOff[2][2];
  #pragma unroll
  for (int mi = 0; mi < 2; ++mi)
    #pragma unroll
    for (int q = 0; q < 2; ++q)
      afOff[mi][q] = ((q * 2 + lhi) * 128 + wy * 64 + mi * 32 + llo) * 8;

  f32x16 acc[2][4];
  #pragma unroll
  for (int mi = 0; mi < 2; ++mi)
    #pragma unroll
    for (int nf = 0; nf < 4; ++nf)
      acc[mi][nf] = (f32x16)(0.f);

  f32x4 R[2][4];   // 2-deep A prefetch ring, 16 f32 each

  auto loadA = [&](int kt, f32x4* r) {
    const float* p = aSrc + kt * BK;
    r[0] = *(const f32x4*)(p);
    r[1] = *(const f32x4*)(p + 4);
    r[2] = *(const f32x4*)(p + 8);
    r[3] = *(const f32x4*)(p + 12);
  };
  auto storeA = [&](int buf, const f32x4* r) {
    half8 h0, h1;
    #pragma unroll
    for (int j = 0; j < 4; ++j) {
      h0[j] = (_Float16)r[0][j]; h0[4 + j] = (_Float16)r[1][j];
      h1[j] = (_Float16)r[2][j]; h1[4 + j] = (_Float16)r[3][j];
    }
    *(half8*)&As[((buf * 4 + akc * 2 + 0) * 128 + arow) * 8] = h0;
    *(half8*)&As[((buf * 4 + akc * 2 + 1) * 128 + arow) * 8] = h1;
  };

  // prologue
  loadA(0, R[0]);
  storeA(0, R[0]);
  loadA(1, R[0]);
  loadA(2, R[1]);
  asm volatile("s_waitcnt lgkmcnt(0)\n\ts_barrier" ::: "memory");

  #pragma unroll 2
  for (int kt = 0; kt < 32; ++kt) {
    const int cur = kt & 1, nxt = cur ^ 1;
    const _Float16* Bkt = Bbase + (size_t)kt * 8192;
    // B frags (direct from L1/L2)
    half8 bf[2][4];
    #pragma unroll
    for (int q = 0; q < 2; ++q)
      #pragma unroll
      for (int nf = 0; nf < 4; ++nf)
        bf[q][nf] = *(const half8*)(Bkt + q * 4096 + nf * 256);
    // A frags from LDS
    half8 af[2][2];
    #pragma unroll
    for (int mi = 0; mi < 2; ++mi)
      #pragma unroll
      for (int q = 0; q < 2; ++q)
        af[mi][q] = *(const half8*)&As[(cur * 4 * 128) * 8 + afOff[mi][q]];
    // MFMAs
    #pragma unroll
    for (int nf = 0; nf < 4; ++nf)
      #pragma unroll
      for (int mi = 0; mi < 2; ++mi)
        #pragma unroll
        for (int q = 0; q < 2; ++q)
          acc[mi][nf] = __builtin_amdgcn_mfma_f32_32x32x16_f16(af[mi][q], bf[q][nf], acc[mi][nf], 0, 0, 0);
    // stage A(kt+1) (regs loaded 2 iters ago), refill ring with A(kt+3)
    if (kt + 1 < 32) storeA(nxt, R[kt & 1]);
    if (kt + 3 < 32) loadA(kt + 3, R[kt & 1]);
    // raw barrier: drain LDS only; global loads stay in flight
    asm volatile("s_waitcnt lgkmcnt(0)\n\ts_barrier" ::: "memory");
  }

  // ---- epilogue: tanh + dot(w_v), reduce over n ----
  // D layout (32x32): col = lane&31 (n), row = (r&3) + 8*(r>>2) + 4*(lane>>5)
  float p[2][16];
  #pragma unroll
  for (int mi = 0; mi < 2; ++mi)
    #pragma unroll
    for (int r = 0; r < 16; ++r) p[mi][r] = 0.f;

  #pragma unroll
  for (int nf = 0; nf < 4; ++nf) {
    const int n = nh * 256 + wx * 128 + nf * 32 + llo;
    const float hb = hproj[b * HD + n] + b_attn[n];
    const float wv = w_v[n];
    #pragma unroll
    for (int mi = 0; mi < 2; ++mi)
      #pragma unroll
      for (int r = 0; r < 16; ++r) {
        float x = fminf(fmaxf(acc[mi][nf][r] + hb, -15.f), 15.f);
        float ex = __expf(2.f * x);
        p[mi][r] += wv * __fdividef(ex - 1.f, ex + 1.f);
      }
  }
  #pragma unroll
  for (int off = 1; off <= 16; off <<= 1)
    #pragma unroll
    for (int mi = 0; mi < 2; ++mi)
      #pragma unroll
      for (int r = 0; r < 16; ++r)
        p[mi][r] += __shfl_xor(p[mi][r], off, 64);

  if (llo == 0) {
    #pragma unroll
    for (int mi = 0; mi < 2; ++mi)
      #pragma unroll
      for (int r = 0; r < 16; ++r) {
        const int m = wy * 64 + mi * 32 + (r & 3) + 8 * (r >> 2) + 4 * lhi;
        atomicAdd(&scores[b * SEQ + s0 + m], p[mi][r]);   // 4 contenders (nh x wx)
      }
  }
}

// ---------- kernel 3: softmax over S, in place ----------
__global__ void softmax_kernel(float* __restrict__ scores) {
  const int b = blockIdx.x;
  float* sc = scores + b * SEQ;
  __shared__ float red[16];
  const int tid = threadIdx.x;   // 256
  float loc[16];
  float mx = -1e30f;
  #pragma unroll
  for (int i = 0; i < 16; ++i) { loc[i] = sc[i * 256 + tid]; mx = fmaxf(mx, loc[i]); }
  #pragma unroll
  for (int off = 32; off >= 1; off >>= 1) mx = fmaxf(mx, __shfl_xor(mx, off, 64));
  if ((tid & 63) == 0) red[tid >> 6] = mx;
  __syncthreads();
  mx = fmaxf(fmaxf(red[0], red[1]), fmaxf(red[2], red[3]));
  float sum = 0.f;
  #pragma unroll
  for (int i = 0; i < 16; ++i) { loc[i] = __expf(loc[i] - mx); sum += loc[i]; }
  #pragma unroll
  for (int off = 32; off >= 1; off >>= 1) sum += __shfl_xor(sum, off, 64);
  if ((tid & 63) == 0) red[8 + (tid >> 6)] = sum;
  __syncthreads();
  sum = red[8] + red[9] + red[10] + red[11];
  const float inv = 1.0f / sum;
  #pragma unroll
  for (int i = 0; i < 16; ++i) sc[i * 256 + tid] = loc[i] * inv;
}

// ---------- kernel 4: context[b,d] = sum_s attn[b,s] * enc[b,s,d] ----------
__global__ __launch_bounds__(256) void context_kernel(const float* __restrict__ attn,
                                                      const float* __restrict__ enc,
                                                      float* __restrict__ out) {
  const int b  = blockIdx.y;
  const int s0 = blockIdx.x * 64;
  const int tid = threadIdx.x;   // 256 threads * float4 = 1024 d
  const float* encB = enc + ((size_t)b * SEQ + s0) * D2 + tid * 4;
  const float* at   = attn + b * SEQ + s0;
  f32x4 acc0 = {0.f, 0.f, 0.f, 0.f}, acc1 = {0.f, 0.f, 0.f, 0.f};
  #pragma unroll 8
  for (int i = 0; i < 64; i += 2) {
    acc0 += at[i]     * *(const f32x4*)(encB + (size_t)i * D2);
    acc1 += at[i + 1] * *(const f32x4*)(encB + (size_t)(i + 1) * D2);
  }
  f32x4 acc = acc0 + acc1;
  float* o = out + b * D2 + tid * 4;
  atomicAdd(o + 0, acc[0]);
  atomicAdd(o + 1, acc[1]);
  atomicAdd(o + 2, acc[2]);
  atomicAdd(o + 3, acc[3]);
}

extern "C" void kernel_launch(void* const* d_in, const int* in_sizes, int n_in,
                              void* d_out, int out_size, void* d_ws, size_t ws_size,
                              hipStream_t stream) {
  (void)in_sizes; (void)n_in; (void)ws_size;
  const float* hidden = (const float*)d_in[0];   // [16,1024]
  const float* enc    = (const float*)d_in[1];   // [16,4096,1024]
  const float* W      = (const float*)d_in[2];   // [2048,512]
  const float* b_attn = (const float*)d_in[3];   // [512]
  const float* w_v    = (const float*)d_in[4];   // [512]
  float* out = (float*)d_out;                    // [16,1024]

  char* ws = (char*)d_ws;
  _Float16* WtS = (_Float16*)ws;                     // 1 MB shuffled Wbot f16
  float* hproj  = (float*)(ws + (1 << 20));          // 32 KB
  float* scores = (float*)(ws + (1 << 20) + 32768);  // 256 KB (reused as attn)

  hipMemsetAsync(d_out, 0, (size_t)out_size * sizeof(float), stream);
  hipMemsetAsync(hproj, 0, BAT * HD * sizeof(float), stream);
  hipMemsetAsync(scores, 0, (size_t)BAT * SEQ * sizeof(float), stream);

  wconv_kernel  <<<dim3(32, 2),             256, 0, stream>>>(W, WtS);
  hproj_kernel  <<<dim3(128),               256, 0, stream>>>(hidden, W, hproj);
  scores_kernel <<<dim3(SEQ / BM, 2, BAT),  256, 0, stream>>>(enc, WtS, hproj, b_attn, w_v, scores);
  softmax_kernel<<<dim3(BAT),               256, 0, stream>>>(scores);
  context_kernel<<<dim3(SEQ / 64, BAT),     256, 0, stream>>>(scores, enc, out);
}

// Round 4
// 496.268 us; speedup vs baseline: 1.0316x; 1.0316x over previous
//
#include <hip/hip_runtime.h>
#include <hip/hip_bf16.h>
#include <math.h>

#define HD   512
#define D2   1024
#define SEQ  4096
#define BAT  16
#define BM   128     // s-rows per block
#define BK   32

typedef _Float16 half8  __attribute__((ext_vector_type(8)));
typedef float    f32x4  __attribute__((ext_vector_type(4)));
typedef float    f32x16 __attribute__((ext_vector_type(16)));
typedef __attribute__((address_space(3))) void lds_void_t;
typedef __attribute__((address_space(1))) void glb_void_t;

// ---------- kernel 0: W bottom-half -> f16, DMA-order chunk-major ----------
// WtS half8-chunk layout: ((nh*32 + kt)*4 + kc)*256 + n
//   chunk value[j] = Wbot[k = kt*32 + (kc>>1)*16 + (kc&1)*8 + j][nh*256 + n]
// This makes scores' B staging a LINEAR global_load_lds copy whose LDS image
// is exactly the B-frag layout (kc = q*2 + lhi), conflict-free on read.
__global__ void wconv_kernel(const float* __restrict__ W, _Float16* __restrict__ WtS) {
  const int kt = blockIdx.x;       // 0..31
  const int nh = blockIdx.y;       // 0..1
  const int t  = threadIdx.x;      // 256 (= n)
  #pragma unroll
  for (int kc = 0; kc < 4; ++kc) {
    half8 h;
    #pragma unroll
    for (int j = 0; j < 8; ++j) {
      const int k = kt * 32 + (kc >> 1) * 16 + (kc & 1) * 8 + j;
      h[j] = (_Float16)W[(size_t)(D2 + k) * HD + nh * 256 + t];   // coalesced in n
    }
    *(half8*)(WtS + (((size_t)(nh * 32 + kt) * 4 + kc) * 256 + t) * 8) = h;
  }
}

// ---------- kernel 1: h_proj[b,h] = hidden[b,:] . W_top[:,h] (atomic) ----------
__global__ void hproj_kernel(const float* __restrict__ hidden,
                             const float* __restrict__ W,
                             float* __restrict__ hproj) {
  const int b  = blockIdx.x >> 3;
  const int kc = blockIdx.x & 7;
  const int h  = threadIdx.x;
  float a0 = 0.f, a1 = 0.f;
  #pragma unroll 4
  for (int i = 0; i < 128; ++i) {
    const int d = kc * 128 + i;
    const float hd = hidden[b * D2 + d];
    a0 += hd * W[(size_t)d * HD + h];
    a1 += hd * W[(size_t)d * HD + h + 256];
  }
  atomicAdd(&hproj[b * HD + h], a0);
  atomicAdd(&hproj[b * HD + h + 256], a1);
}

// ---------- kernel 2: scores = w_v . tanh(enc.Wbot + h_proj + b_attn) ----------
// 4 waves; wave tile 64x128 (Fm=2, Fn=4 of mfma_f32_32x32x16_f16), block 128x256.
// A: f32 global -> 2-deep reg ring -> cvt f16 -> LDS double buffer (chunk-major).
// B: global_load_lds double buffer from pre-shuffled WtS (8 KB/block/kt).
// One __syncthreads per kt (m97 structure).
__global__ __launch_bounds__(256, 2) void scores_kernel(
    const float* __restrict__ enc, const _Float16* __restrict__ WtS,
    const float* __restrict__ hproj, const float* __restrict__ b_attn,
    const float* __restrict__ w_v, float* __restrict__ scores)
{
  // As: [buf][kc(4)][row(128)][8 f16] = 8 KB per buf
  // Bs: [buf][kc(4)][n(256)][8 f16]  = 16 KB per buf
  __shared__ __align__(16) _Float16 As[2][4 * 128 * 8];
  __shared__ __align__(16) _Float16 Bs[2][4 * 256 * 8];

  const int s0   = blockIdx.x * BM;
  const int nh   = blockIdx.y;
  const int b    = blockIdx.z;
  const int tid  = threadIdx.x, lane = tid & 63, w = tid >> 6;
  const int wy   = w >> 1, wx = w & 1;
  const int llo  = lane & 31, lhi = lane >> 5;

  const float* encB = enc + ((size_t)b * SEQ + s0) * D2;

  // A staging: thread t loads 16 f32 of row (t>>1), k-half (t&1)
  const int arow = tid >> 1, akh = tid & 1;
  const float* aSrc = encB + (size_t)arow * D2 + akh * 16;

  const _Float16* WtB = WtS + (size_t)nh * 32 * 8192;   // + kt*8192 halves

  // A-frag read offsets (halves): chunk kc = q*2+lhi, row = wy*64+mi*32+llo
  int afOff[2][2];
  #pragma unroll
  for (int mi = 0; mi < 2; ++mi)
    #pragma unroll
    for (int q = 0; q < 2; ++q)
      afOff[mi][q] = (((q * 2 + lhi) * 128) + wy * 64 + mi * 32 + llo) * 8;
  // B-frag read offsets (halves): chunk kc = q*2+lhi, n = wx*128+nf*32+llo
  int bfOff[2][4];
  #pragma unroll
  for (int q = 0; q < 2; ++q)
    #pragma unroll
    for (int nf = 0; nf < 4; ++nf)
      bfOff[q][nf] = (((q * 2 + lhi) * 256) + wx * 128 + nf * 32 + llo) * 8;

  f32x16 acc[2][4];
  #pragma unroll
  for (int mi = 0; mi < 2; ++mi)
    #pragma unroll
    for (int nf = 0; nf < 4; ++nf)
      acc[mi][nf] = (f32x16)(0.f);

  f32x4 R[2][4];   // 2-deep A prefetch ring

  auto loadA = [&](int kt, f32x4* r) {
    const float* p = aSrc + kt * BK;
    r[0] = *(const f32x4*)(p);
    r[1] = *(const f32x4*)(p + 4);
    r[2] = *(const f32x4*)(p + 8);
    r[3] = *(const f32x4*)(p + 12);
  };
  auto storeA = [&](int buf, const f32x4* r) {
    half8 h0, h1;
    #pragma unroll
    for (int j = 0; j < 4; ++j) {
      h0[j] = (_Float16)r[0][j]; h0[4 + j] = (_Float16)r[1][j];
      h1[j] = (_Float16)r[2][j]; h1[4 + j] = (_Float16)r[3][j];
    }
    *(half8*)&As[buf][((akh * 2 + 0) * 128 + arow) * 8] = h0;
    *(half8*)&As[buf][((akh * 2 + 1) * 128 + arow) * 8] = h1;
  };
  auto issueB = [&](int kt, int buf) {
    #pragma unroll
    for (int i = 0; i < 4; ++i) {
      const int c = i * 256 + tid;
      __builtin_amdgcn_global_load_lds(
          (glb_void_t*)(WtB + ((size_t)kt * 1024 + c) * 8),
          (lds_void_t*)((char*)&Bs[buf][0] + c * 16), 16, 0, 0);
    }
  };

  // prologue: invariant entering kt: R[kt&1]=A(kt+1), R[(kt+1)&1]=A(kt+2)
  loadA(0, R[0]);
  storeA(0, R[0]);
  issueB(0, 0);
  loadA(1, R[0]);
  loadA(2, R[1]);
  __syncthreads();

  #pragma unroll 2
  for (int kt = 0; kt < 32; ++kt) {
    const int cur = kt & 1, nxt = cur ^ 1;
    if (kt + 1 < 32) { storeA(nxt, R[cur]); issueB(kt + 1, nxt); }
    if (kt + 3 < 32) loadA(kt + 3, R[cur]);
    // compute on cur
    half8 af[2][2], bf[2][4];
    #pragma unroll
    for (int mi = 0; mi < 2; ++mi)
      #pragma unroll
      for (int q = 0; q < 2; ++q)
        af[mi][q] = *(const half8*)&As[cur][afOff[mi][q]];
    #pragma unroll
    for (int q = 0; q < 2; ++q)
      #pragma unroll
      for (int nf = 0; nf < 4; ++nf)
        bf[q][nf] = *(const half8*)&Bs[cur][bfOff[q][nf]];
    #pragma unroll
    for (int nf = 0; nf < 4; ++nf)
      #pragma unroll
      for (int mi = 0; mi < 2; ++mi)
        #pragma unroll
        for (int q = 0; q < 2; ++q)
          acc[mi][nf] = __builtin_amdgcn_mfma_f32_32x32x16_f16(af[mi][q], bf[q][nf], acc[mi][nf], 0, 0, 0);
    __syncthreads();
  }

  // ---- epilogue: tanh + dot(w_v), reduce over n (verified in R3) ----
  // D layout (32x32): col = lane&31 (n), row = (r&3) + 8*(r>>2) + 4*(lane>>5)
  float p[2][16];
  #pragma unroll
  for (int mi = 0; mi < 2; ++mi)
    #pragma unroll
    for (int r = 0; r < 16; ++r) p[mi][r] = 0.f;

  #pragma unroll
  for (int nf = 0; nf < 4; ++nf) {
    const int n = nh * 256 + wx * 128 + nf * 32 + llo;
    const float hb = hproj[b * HD + n] + b_attn[n];
    const float wv = w_v[n];
    #pragma unroll
    for (int mi = 0; mi < 2; ++mi)
      #pragma unroll
      for (int r = 0; r < 16; ++r) {
        float x = fminf(fmaxf(acc[mi][nf][r] + hb, -15.f), 15.f);
        float ex = __expf(2.f * x);
        p[mi][r] += wv * __fdividef(ex - 1.f, ex + 1.f);
      }
  }
  #pragma unroll
  for (int off = 1; off <= 16; off <<= 1)
    #pragma unroll
    for (int mi = 0; mi < 2; ++mi)
      #pragma unroll
      for (int r = 0; r < 16; ++r)
        p[mi][r] += __shfl_xor(p[mi][r], off, 64);

  if (llo == 0) {
    #pragma unroll
    for (int mi = 0; mi < 2; ++mi)
      #pragma unroll
      for (int r = 0; r < 16; ++r) {
        const int m = wy * 64 + mi * 32 + (r & 3) + 8 * (r >> 2) + 4 * lhi;
        atomicAdd(&scores[b * SEQ + s0 + m], p[mi][r]);   // 4 contenders (nh x wx)
      }
  }
}

// ---------- kernel 3: softmax over S, in place ----------
__global__ void softmax_kernel(float* __restrict__ scores) {
  const int b = blockIdx.x;
  float* sc = scores + b * SEQ;
  __shared__ float red[16];
  const int tid = threadIdx.x;   // 256
  float loc[16];
  float mx = -1e30f;
  #pragma unroll
  for (int i = 0; i < 16; ++i) { loc[i] = sc[i * 256 + tid]; mx = fmaxf(mx, loc[i]); }
  #pragma unroll
  for (int off = 32; off >= 1; off >>= 1) mx = fmaxf(mx, __shfl_xor(mx, off, 64));
  if ((tid & 63) == 0) red[tid >> 6] = mx;
  __syncthreads();
  mx = fmaxf(fmaxf(red[0], red[1]), fmaxf(red[2], red[3]));
  float sum = 0.f;
  #pragma unroll
  for (int i = 0; i < 16; ++i) { loc[i] = __expf(loc[i] - mx); sum += loc[i]; }
  #pragma unroll
  for (int off = 32; off >= 1; off >>= 1) sum += __shfl_xor(sum, off, 64);
  if ((tid & 63) == 0) red[8 + (tid >> 6)] = sum;
  __syncthreads();
  sum = red[8] + red[9] + red[10] + red[11];
  const float inv = 1.0f / sum;
  #pragma unroll
  for (int i = 0; i < 16; ++i) sc[i * 256 + tid] = loc[i] * inv;
}

// ---------- kernel 4: context[b,d] = sum_s attn[b,s] * enc[b,s,d] ----------
__global__ __launch_bounds__(256) void context_kernel(const float* __restrict__ attn,
                                                      const float* __restrict__ enc,
                                                      float* __restrict__ out) {
  const int b  = blockIdx.y;
  const int s0 = blockIdx.x * 64;
  const int tid = threadIdx.x;   // 256 threads * float4 = 1024 d
  const float* encB = enc + ((size_t)b * SEQ + s0) * D2 + tid * 4;
  const float* at   = attn + b * SEQ + s0;
  f32x4 acc0 = {0.f, 0.f, 0.f, 0.f}, acc1 = {0.f, 0.f, 0.f, 0.f};
  #pragma unroll 8
  for (int i = 0; i < 64; i += 2) {
    acc0 += at[i]     * *(const f32x4*)(encB + (size_t)i * D2);
    acc1 += at[i + 1] * *(const f32x4*)(encB + (size_t)(i + 1) * D2);
  }
  f32x4 acc = acc0 + acc1;
  float* o = out + b * D2 + tid * 4;
  atomicAdd(o + 0, acc[0]);
  atomicAdd(o + 1, acc[1]);
  atomicAdd(o + 2, acc[2]);
  atomicAdd(o + 3, acc[3]);
}

extern "C" void kernel_launch(void* const* d_in, const int* in_sizes, int n_in,
                              void* d_out, int out_size, void* d_ws, size_t ws_size,
                              hipStream_t stream) {
  (void)in_sizes; (void)n_in; (void)ws_size;
  const float* hidden = (const float*)d_in[0];   // [16,1024]
  const float* enc    = (const float*)d_in[1];   // [16,4096,1024]
  const float* W      = (const float*)d_in[2];   // [2048,512]
  const float* b_attn = (const float*)d_in[3];   // [512]
  const float* w_v    = (const float*)d_in[4];   // [512]
  float* out = (float*)d_out;                    // [16,1024]

  char* ws = (char*)d_ws;
  _Float16* WtS = (_Float16*)ws;                     // 1 MB shuffled Wbot f16
  float* hproj  = (float*)(ws + (1 << 20));          // 32 KB
  float* scores = (float*)(ws + (1 << 20) + 32768);  // 256 KB (reused as attn)

  hipMemsetAsync(d_out, 0, (size_t)out_size * sizeof(float), stream);
  hipMemsetAsync(hproj, 0, BAT * HD * sizeof(float), stream);
  hipMemsetAsync(scores, 0, (size_t)BAT * SEQ * sizeof(float), stream);

  wconv_kernel  <<<dim3(32, 2),             256, 0, stream>>>(W, WtS);
  hproj_kernel  <<<dim3(128),               256, 0, stream>>>(hidden, W, hproj);
  scores_kernel <<<dim3(SEQ / BM, 2, BAT),  256, 0, stream>>>(enc, WtS, hproj, b_attn, w_v, scores);
  softmax_kernel<<<dim3(BAT),               256, 0, stream>>>(scores);
  context_kernel<<<dim3(SEQ / 64, BAT),     256, 0, stream>>>(scores, enc, out);
}